// Round 1
// baseline (648.227 us; speedup 1.0000x reference)
//
#include <hip/hip_runtime.h>

// SAGEConv (cugraph SAGEConvAgg, mean aggregation, root_weight concat):
//   agg[n]  = mean_{e: dst[e]==n} x[src[e]]
//   out     = concat(agg, x) @ W.T + b        W: [64,128], b: [64]
// Inputs: d_in[0]=x fp32 [100000,64], d_in[1]=edge_index int [2,1.6M],
//         d_in[2]=num_nodes (scalar), d_in[3]=W fp32 [64,128], d_in[4]=b fp32 [64]

constexpr int FIN = 64;
constexpr int FOUT = 64;

// --- degree histogram ---------------------------------------------------
__global__ __launch_bounds__(256) void k_deg(const int* __restrict__ dst,
                                             float* __restrict__ deg, int n_edges) {
    int e = blockIdx.x * 256 + threadIdx.x;
    if (e < n_edges) unsafeAtomicAdd(&deg[dst[e]], 1.0f);
}

// --- feature scatter-add: one wave per edge, lane = feature -------------
__global__ __launch_bounds__(256) void k_scatter(const float* __restrict__ x,
                                                 const int* __restrict__ src,
                                                 const int* __restrict__ dst,
                                                 float* __restrict__ agg, int n_edges) {
    unsigned long long tid = (unsigned long long)blockIdx.x * 256ull + threadIdx.x;
    int e = (int)(tid >> 6);
    int f = (int)(tid & 63);
    if (e < n_edges) {
        int s = src[e];   // broadcast load within the wave
        int d = dst[e];
        unsafeAtomicAdd(&agg[(size_t)d * FIN + f], x[(size_t)s * FIN + f]);
    }
}

// --- fused mean + concat + GEMM -----------------------------------------
// lane = node (128 nodes per 256-thread block; waves 0-1 compute out cols
// 0..31, waves 2-3 cols 32..63 so the W row index stays wave-uniform and
// W is fetched through the scalar cache via s_load).
__global__ __launch_bounds__(256) void k_out(const float* __restrict__ x,
                                             const float* __restrict__ agg,
                                             const float* __restrict__ deg,
                                             const float* __restrict__ W,
                                             const float* __restrict__ b,
                                             float* __restrict__ out, int n_nodes) {
    int local = threadIdx.x & 127;
    int half  = threadIdx.x >> 7;          // wave-uniform: waves 0,1 -> 0; 2,3 -> 1
    int n = blockIdx.x * 128 + local;
    if (n >= n_nodes) return;

    float dinv = 1.0f / fmaxf(deg[n], 1.0f);

    float acc[32];
#pragma unroll
    for (int j = 0; j < 32; ++j) acc[j] = b[half * 32 + j];   // uniform -> s_load

    const float* rowa = agg + (size_t)n * FIN;
    const float* rowx = x   + (size_t)n * FIN;

    for (int c = 0; c < 4; ++c) {          // K chunks of 32 (0,1: agg; 2,3: x)
        const float* rsrc = (c < 2) ? (rowa + c * 32) : (rowx + (c - 2) * 32);
        float hr[32];
#pragma unroll
        for (int i = 0; i < 8; ++i) {
            float4 v = ((const float4*)rsrc)[i];
            hr[4 * i] = v.x; hr[4 * i + 1] = v.y; hr[4 * i + 2] = v.z; hr[4 * i + 3] = v.w;
        }
        if (c < 2) {
#pragma unroll
            for (int i = 0; i < 32; ++i) hr[i] *= dinv;
        }
        const float* wbase = W + c * 32;
#pragma unroll
        for (int j = 0; j < 32; ++j) {
            const float* wr = wbase + (size_t)(half * 32 + j) * 128;  // uniform row
#pragma unroll
            for (int kk = 0; kk < 32; ++kk) {
                acc[j] = fmaf(hr[kk], wr[kk], acc[j]);
            }
        }
    }

    float4* o = (float4*)(out + (size_t)n * FOUT + half * 32);
#pragma unroll
    for (int j = 0; j < 8; ++j) {
        o[j] = make_float4(acc[4 * j], acc[4 * j + 1], acc[4 * j + 2], acc[4 * j + 3]);
    }
}

extern "C" void kernel_launch(void* const* d_in, const int* in_sizes, int n_in,
                              void* d_out, int out_size, void* d_ws, size_t ws_size,
                              hipStream_t stream) {
    const float* x  = (const float*)d_in[0];
    const int*   ei = (const int*)d_in[1];
    const float* W  = (const float*)d_in[3];
    const float* b  = (const float*)d_in[4];
    float* out = (float*)d_out;

    int n_nodes = in_sizes[0] / FIN;
    int n_edges = in_sizes[1] / 2;
    const int* src = ei;             // edge_index[0]
    const int* dst = ei + n_edges;   // edge_index[1]

    float* agg = (float*)d_ws;                          // [n_nodes, 64]
    float* deg = agg + (size_t)n_nodes * FIN;           // [n_nodes]

    size_t zero_bytes = ((size_t)n_nodes * FIN + (size_t)n_nodes) * sizeof(float);
    hipMemsetAsync(d_ws, 0, zero_bytes, stream);

    k_deg<<<(n_edges + 255) / 256, 256, 0, stream>>>(dst, deg, n_edges);

    long long total = (long long)n_edges * 64;
    int blocks = (int)((total + 255) / 256);
    k_scatter<<<blocks, 256, 0, stream>>>(x, src, dst, agg, n_edges);

    k_out<<<(n_nodes + 127) / 128, 256, 0, stream>>>(x, agg, deg, W, b, out, n_nodes);
}

// Round 2
// 466.130 us; speedup vs baseline: 1.3907x; 1.3907x over previous
//
#include <hip/hip_runtime.h>

// SAGEConv mean-agg + concat-linear, CSR gather formulation (no feature atomics):
//   1. deg[n]       = #in-edges (int atomics, 400KB array)
//   2. row_start    = exclusive scan of deg (atomic block-base alloc; node
//                     ranges need not be in node order, only self-consistent)
//   3. csr_src      = src ids bucketed per dst (cursor atomics)
//   4. fused: one wave per node — lane=feature gathers+sums x[src] rows,
//      then lane=out-col GEMM via __shfl broadcast of h against a
//      register-resident W row (128 VGPRs/lane, amortized by grid-stride).

constexpr int FIN  = 64;
constexpr int FOUT = 64;

__global__ __launch_bounds__(256) void k_deg(const int* __restrict__ dst,
                                             int* __restrict__ deg, int n_edges) {
    int e = blockIdx.x * 256 + threadIdx.x;
    if (e < n_edges) atomicAdd(&deg[dst[e]], 1);
}

// exclusive scan, 1024 elems/block, block base allocated via atomicAdd(total)
__global__ __launch_bounds__(256) void k_scan(const int* __restrict__ deg,
                                              int* __restrict__ row_start,
                                              int* __restrict__ total, int n) {
    __shared__ int sc[256];
    __shared__ int gbase;
    int t = threadIdx.x;
    int i0 = blockIdx.x * 1024 + t * 4;
    int v0 = 0, v1 = 0, v2 = 0, v3 = 0;
    if (i0 + 3 < n) {
        int4 q = *(const int4*)(deg + i0);
        v0 = q.x; v1 = q.y; v2 = q.z; v3 = q.w;
    } else {
        if (i0     < n) v0 = deg[i0];
        if (i0 + 1 < n) v1 = deg[i0 + 1];
        if (i0 + 2 < n) v2 = deg[i0 + 2];
        if (i0 + 3 < n) v3 = deg[i0 + 3];
    }
    int tsum = v0 + v1 + v2 + v3;
    sc[t] = tsum;
    __syncthreads();
    for (int off = 1; off < 256; off <<= 1) {   // Hillis-Steele inclusive
        int tmp = (t >= off) ? sc[t - off] : 0;
        __syncthreads();
        sc[t] += tmp;
        __syncthreads();
    }
    if (t == 255) gbase = atomicAdd(total, sc[255]);
    int excl = sc[t] - tsum;
    __syncthreads();
    int base = gbase + excl;
    if (i0     < n) row_start[i0]     = base;  base += v0;
    if (i0 + 1 < n) row_start[i0 + 1] = base;  base += v1;
    if (i0 + 2 < n) row_start[i0 + 2] = base;  base += v2;
    if (i0 + 3 < n) row_start[i0 + 3] = base;
}

__global__ __launch_bounds__(256) void k_fill(const int* __restrict__ src,
                                              const int* __restrict__ dst,
                                              const int* __restrict__ row_start,
                                              int* __restrict__ cursor,
                                              int* __restrict__ csr, int n_edges) {
    int e = blockIdx.x * 256 + threadIdx.x;
    if (e < n_edges) {
        int d = dst[e];
        int pos = atomicAdd(&cursor[d], 1);
        csr[row_start[d] + pos] = src[e];
    }
}

// one wave per node (grid-stride). Aggregate with lane=feature, then GEMM with
// lane=output-column; h broadcast across the wave via __shfl.
__global__ __launch_bounds__(256) void k_agg_out(const float* __restrict__ x,
                                                 const int* __restrict__ row_start,
                                                 const int* __restrict__ deg,
                                                 const int* __restrict__ csr,
                                                 const float* __restrict__ W,
                                                 const float* __restrict__ b,
                                                 float* __restrict__ out, int n_nodes) {
    int lane   = threadIdx.x & 63;
    int wid    = blockIdx.x * 4 + (threadIdx.x >> 6);
    int nwaves = gridDim.x * 4;

    // W row `lane` -> 128 VGPRs (one-time per wave; grid-stride amortizes)
    float wreg[128];
    const float4* wrow = (const float4*)(W + (size_t)lane * 128);
#pragma unroll
    for (int i = 0; i < 32; ++i) {
        float4 q = wrow[i];
        wreg[4*i] = q.x; wreg[4*i+1] = q.y; wreg[4*i+2] = q.z; wreg[4*i+3] = q.w;
    }
    float breg = b[lane];

    for (int n = wid; n < n_nodes; n += nwaves) {
        int start = row_start[n];   // wave-uniform -> scalar loads
        int d     = deg[n];
        float acc = 0.0f;
        for (int base = 0; base < d; base += 64) {
            int cnt  = min(64, d - base);
            int sidx = csr[start + base + ((lane < cnt) ? lane : 0)];  // coalesced
            int j = 0;
            for (; j + 4 <= cnt; j += 4) {       // 4 gathers in flight
                int s0 = __shfl(sidx, j),     s1 = __shfl(sidx, j + 1);
                int s2 = __shfl(sidx, j + 2), s3 = __shfl(sidx, j + 3);
                float v0 = x[(size_t)s0 * FIN + lane];
                float v1 = x[(size_t)s1 * FIN + lane];
                float v2 = x[(size_t)s2 * FIN + lane];
                float v3 = x[(size_t)s3 * FIN + lane];
                acc += (v0 + v1) + (v2 + v3);
            }
            for (; j < cnt; ++j) {
                int s = __shfl(sidx, j);
                acc += x[(size_t)s * FIN + lane];
            }
        }
        float dinv = 1.0f / fmaxf((float)d, 1.0f);
        float hl = acc * dinv;                    // agg feature `lane`
        float hs = x[(size_t)n * FIN + lane];     // self feature `lane`

        float o = breg;                           // lane = output column
#pragma unroll
        for (int f = 0; f < 64; ++f) {
            o = fmaf(__shfl(hl, f), wreg[f],      o);
            o = fmaf(__shfl(hs, f), wreg[64 + f], o);
        }
        out[(size_t)n * FOUT + lane] = o;
    }
}

extern "C" void kernel_launch(void* const* d_in, const int* in_sizes, int n_in,
                              void* d_out, int out_size, void* d_ws, size_t ws_size,
                              hipStream_t stream) {
    const float* x  = (const float*)d_in[0];
    const int*   ei = (const int*)d_in[1];
    const float* W  = (const float*)d_in[3];
    const float* b  = (const float*)d_in[4];
    float* out = (float*)d_out;

    int n_nodes = in_sizes[0] / FIN;
    int n_edges = in_sizes[1] / 2;
    const int* src = ei;
    const int* dst = ei + n_edges;

    // ws layout (ints): deg[N] | cursor[N] | total[1]+pad | row_start[N] | csr[E]
    int* wsi       = (int*)d_ws;
    int* deg       = wsi;
    int* cursor    = wsi + n_nodes;
    int* total     = wsi + 2 * n_nodes;
    int* row_start = wsi + 2 * n_nodes + 4;       // 16B-aligned
    int* csr       = wsi + 3 * n_nodes + 4;

    hipMemsetAsync(d_ws, 0, (size_t)(2 * n_nodes + 4) * sizeof(int), stream);

    int eb = (n_edges + 255) / 256;
    k_deg<<<eb, 256, 0, stream>>>(dst, deg, n_edges);
    k_scan<<<(n_nodes + 1023) / 1024, 256, 0, stream>>>(deg, row_start, total, n_nodes);
    k_fill<<<eb, 256, 0, stream>>>(src, dst, row_start, cursor, csr, n_edges);
    k_agg_out<<<1024, 256, 0, stream>>>(x, row_start, deg, csr, W, b, out, n_nodes);
}